// Round 1
// baseline (488.549 us; speedup 1.0000x reference)
//
#include <hip/hip_runtime.h>

// Problem constants (from reference)
constexpr int I_N = 3, H_N = 2048, O_N = 2, S_N = 4, G_N = 7;
constexpr int B_N = 32, T_N = 512;
constexpr int TPB = 512;          // threads per block (8 waves)
constexpr int EPT = H_N / TPB;    // 4 consecutive h-elements per thread
constexpr int NWAVE = TPB / 64;   // 8
constexpr float ALPHA_C = 0.2f;
constexpr float NSTD_C = 0.05f;

// tanh(x) = 1 - 2/(exp(2x)+1)  (exact identity; inf-safe at both ends)
__device__ __forceinline__ float fast_tanh(float x) {
  float e = __expf(2.0f * x);
  return fmaf(-2.0f, __builtin_amdgcn_rcpf(e + 1.0f), 1.0f);
}

#define DPP_ADD(x, ctrl, rmask)                                                  \
  x += __int_as_float(__builtin_amdgcn_update_dpp(                               \
      0, __float_as_int(x), (ctrl), (rmask), 0xf, true))

// Full 64-lane sum ends up in lane 63 (classic GCN row_shr/bcast ladder).
__device__ __forceinline__ float wave_sum63(float x) {
  DPP_ADD(x, 0x111, 0xf);  // row_shr:1
  DPP_ADD(x, 0x112, 0xf);  // row_shr:2
  DPP_ADD(x, 0x114, 0xf);  // row_shr:4
  DPP_ADD(x, 0x118, 0xf);  // row_shr:8  -> lane15 of each row16 has row sum
  DPP_ADD(x, 0x142, 0xa);  // row_bcast15 -> lane31 has sum(0..31)
  DPP_ADD(x, 0x143, 0xc);  // row_bcast31 -> lane63 has sum(0..63)
  return x;
}

__device__ __forceinline__ float rdlane(float v, int l) {
  return __int_as_float(__builtin_amdgcn_readlane(__float_as_int(v), l));
}

__global__ __launch_bounds__(TPB) void rnn_fused(
    const float* __restrict__ input,   // (B,T,I)
    const float* __restrict__ noise,   // (B,T,H)
    const float* __restrict__ wi,      // (I,S,G)
    const float* __restrict__ unitwi,  // (I,S,1)
    const float* __restrict__ m_,      // (R,S,G)
    const float* __restrict__ n_,      // (R,S,G)
    const float* __restrict__ unitm,   // (R,S,1)
    const float* __restrict__ unitn,   // (R,S,1)
    const float* __restrict__ wo,      // (O,S,G)
    const float* __restrict__ h0,      // (S,G)
    const float* __restrict__ unith0,  // (S,1)
    const float* __restrict__ bias,    // (S,1)
    const float* __restrict__ gb,      // (G,H)
    const float* __restrict__ uv,      // (1,H)
    const float* __restrict__ sup,     // (S,H)
    float* __restrict__ out,           // (B,T,O)
    float* __restrict__ traj) {        // (B,T,H)
  const int tid = threadIdx.x;
  const int lane = tid & 63;
  const int wave = tid >> 6;
  const int b = blockIdx.x;
  const int hbase = tid * EPT;
  const int s = hbase >> 9;  // H/S = 512; all 4 elems share the same support

  __shared__ float partials[2][NWAVE * 4];  // double-buffered per-wave partials

  // ---- setup: per-element proxy constants (one-time, L1-broadcast loads) ----
  float cn0[EPT], cn1[EPT], cm0[EPT], cm1[EPT];
  float cw0[EPT], cw1[EPT], cw2[EPT];
  float co0[EPT], co1[EPT], cb[EPT], h[EPT], r[EPT];

  for (int e = 0; e < EPT; ++e) {
    const int hh = hbase + e;
    float gbh[G_N];
#pragma unroll
    for (int g = 0; g < G_N; ++g) gbh[g] = gb[g * H_N + hh];
    const float uvh = uv[hh];
    const float sv = sup[s * H_N + hh];  // ==1 on own support block (partition)

    auto comb = [&](const float* p, const float* up, int k) {
      float acc = up[k * S_N + s] * uvh;
#pragma unroll
      for (int g = 0; g < G_N; ++g)
        acc = fmaf(p[(k * S_N + s) * G_N + g], gbh[g], acc);
      return acc * sv;
    };
    auto combNoU = [&](const float* p, int k) {
      float acc = 0.0f;
#pragma unroll
      for (int g = 0; g < G_N; ++g)
        acc = fmaf(p[(k * S_N + s) * G_N + g], gbh[g], acc);
      return acc * sv;
    };

    cn0[e] = comb(n_, unitn, 0);            // n_rec[h][0]
    cn1[e] = comb(n_, unitn, 1);            // n_rec[h][1]
    cm0[e] = ALPHA_C * comb(m_, unitm, 0);  // ALPHA * m_rec[h][0]
    cm1[e] = ALPHA_C * comb(m_, unitm, 1);
    cw0[e] = ALPHA_C * comb(wi, unitwi, 0); // ALPHA * wi_full[i][h]
    cw1[e] = ALPHA_C * comb(wi, unitwi, 1);
    cw2[e] = ALPHA_C * comb(wi, unitwi, 2);
    co0[e] = combNoU(wo, 0);                // wo_full[h][0]
    co1[e] = combNoU(wo, 1);
    cb[e] = bias[s] * uvh * sv;             // bias_full[h]
    h[e] = comb(h0, unith0, 0);             // h0_full[h]
    r[e] = fast_tanh(h[e]);
  }

  const float* zp = noise + ((size_t)b * T_N) * H_N + hbase;
  const float* xp = input + ((size_t)b * T_N) * I_N;
  float* tp = traj + ((size_t)b * T_N) * H_N + hbase;
  float* op = out + ((size_t)b * T_N) * O_N;

  float4 zc = *(const float4*)zp;  // z_0
  float x0 = xp[0], x1 = xp[1], x2 = xp[2];  // x_0

  __builtin_amdgcn_s_waitcnt(0xC07F);  // lgkmcnt(0): LDS consistent before loop
  __builtin_amdgcn_s_barrier();

#pragma unroll 2
  for (int t = 0; t < T_N; ++t) {
    // prefetch next step's z (vector) and x (uniform -> scalar loads)
    const int tn = (t + 1 < T_N) ? t + 1 : t;
    float4 zn = *(const float4*)(zp + (size_t)tn * H_N);
    const float* xq = xp + tn * I_N;
    float nx0 = xq[0], nx1 = xq[1], nx2 = xq[2];

    // 4 dot-partials over this thread's elements: a0,a1 (recurrence), o0,o1 (out_{t-1})
    float pa0 = 0.f, pa1 = 0.f, po0 = 0.f, po1 = 0.f;
#pragma unroll
    for (int e = 0; e < EPT; ++e) {
      pa0 = fmaf(r[e], cn0[e], pa0);
      pa1 = fmaf(r[e], cn1[e], pa1);
      po0 = fmaf(r[e], co0[e], po0);
      po1 = fmaf(r[e], co1[e], po1);
    }
    // wave-level reduce (VALU/DPP, no LDS pipe)
    pa0 = wave_sum63(pa0);
    pa1 = wave_sum63(pa1);
    po0 = wave_sum63(po0);
    po1 = wave_sum63(po1);
    const int pb = t & 1;
    if (lane == 63) {
      float4 v4 = make_float4(pa0, pa1, po0, po1);
      *(float4*)&partials[pb][wave * 4] = v4;
    }
    __builtin_amdgcn_s_waitcnt(0xC07F);  // lgkmcnt(0) only; do NOT drain vmcnt
    __builtin_amdgcn_s_barrier();

    // cross-wave: 8 waves x 4 vals = 32 floats; reduce across wave index
    float v = partials[pb][lane & 31];
    DPP_ADD(v, 0x124, 0xf);  // row_ror:4
    DPP_ADD(v, 0x128, 0xf);  // row_ror:8  -> per-row sum over w for each j=lane&3
    v += __int_as_float(__builtin_amdgcn_ds_swizzle(__float_as_int(v), 0x401F));  // xor16
    const float a0 = rdlane(v, 0);
    const float a1 = rdlane(v, 1);
    const float o0 = rdlane(v, 2);
    const float o1 = rdlane(v, 3);

    if (tid == 0 && t > 0) ((float2*)op)[t - 1] = make_float2(o0, o1);

    // h <- 0.8h + bias + 0.05 z + ALPHA*(a0 m0 + a1 m1 + x.wi)
    float ze[EPT] = {zc.x, zc.y, zc.z, zc.w};
#pragma unroll
    for (int e = 0; e < EPT; ++e) {
      float u = fmaf(NSTD_C, ze[e], cb[e]);
      u = fmaf(x0, cw0[e], u);
      u = fmaf(x1, cw1[e], u);
      u = fmaf(x2, cw2[e], u);
      u = fmaf(a0, cm0[e], u);
      u = fmaf(a1, cm1[e], u);
      h[e] = fmaf(1.0f - ALPHA_C, h[e], u);
    }
    *(float4*)(tp + (size_t)t * H_N) = make_float4(h[0], h[1], h[2], h[3]);
#pragma unroll
    for (int e = 0; e < EPT; ++e) r[e] = fast_tanh(h[e]);

    zc = zn; x0 = nx0; x1 = nx1; x2 = nx2;
  }

  // tail: out[T-1] = tanh(h_T) @ wo
  {
    float po0 = 0.f, po1 = 0.f;
#pragma unroll
    for (int e = 0; e < EPT; ++e) {
      po0 = fmaf(r[e], co0[e], po0);
      po1 = fmaf(r[e], co1[e], po1);
    }
    po0 = wave_sum63(po0);
    po1 = wave_sum63(po1);
    if (lane == 63) {
      partials[0][wave * 4 + 2] = po0;
      partials[0][wave * 4 + 3] = po1;
    }
    __builtin_amdgcn_s_waitcnt(0xC07F);
    __builtin_amdgcn_s_barrier();
    if (tid == 0) {
      float o0 = 0.f, o1 = 0.f;
#pragma unroll
      for (int w = 0; w < NWAVE; ++w) {
        o0 += partials[0][w * 4 + 2];
        o1 += partials[0][w * 4 + 3];
      }
      ((float2*)op)[T_N - 1] = make_float2(o0, o1);
    }
  }
}

extern "C" void kernel_launch(void* const* d_in, const int* in_sizes, int n_in,
                              void* d_out, int out_size, void* d_ws, size_t ws_size,
                              hipStream_t stream) {
  const float* input  = (const float*)d_in[0];
  const float* noise  = (const float*)d_in[1];
  const float* wi     = (const float*)d_in[2];
  const float* unitwi = (const float*)d_in[3];
  const float* m_     = (const float*)d_in[4];
  const float* n_     = (const float*)d_in[5];
  const float* unitm  = (const float*)d_in[6];
  const float* unitn  = (const float*)d_in[7];
  const float* wo     = (const float*)d_in[8];
  const float* h0     = (const float*)d_in[9];
  const float* unith0 = (const float*)d_in[10];
  const float* bias   = (const float*)d_in[11];
  const float* gb     = (const float*)d_in[12];
  const float* uv     = (const float*)d_in[13];
  const float* sup    = (const float*)d_in[14];

  float* out  = (float*)d_out;                       // (B,T,O) first
  float* traj = out + (size_t)B_N * T_N * O_N;       // then (B,T,H)

  rnn_fused<<<dim3(B_N), dim3(TPB), 0, stream>>>(
      input, noise, wi, unitwi, m_, n_, unitm, unitn, wo, h0, unith0, bias,
      gb, uv, sup, out, traj);
}